// Round 10
// baseline (759.858 us; speedup 1.0000x reference)
//
#include <hip/hip_runtime.h>
#include <hip/hip_bf16.h>

typedef unsigned short u16;
typedef unsigned char  u8;
typedef __attribute__((ext_vector_type(4))) float floatx4;  // MFMA C/D frag

#define LN_EPS 1e-5f

__device__ __forceinline__ float bf2f(u16 u) {
    unsigned int i = ((unsigned int)u) << 16;
    float f; __builtin_memcpy(&f, &i, 4); return f;
}
__device__ __forceinline__ u16 f2bf(float f) {
    __hip_bfloat16 h = __float2bfloat16(f);   // RNE
    u16 u; __builtin_memcpy(&u, &h, 2); return u;
}
// f32 -> OCP e4m3fn via HW packed convert (self-consistent with fp8 MFMA)
__device__ __forceinline__ u8 f2e4(float f) {
    int p = __builtin_amdgcn_cvt_pk_fp8_f32(f, f, 0, false);
    return (u8)(p & 0xff);
}

// GEMM-operand global pre-swizzle (ALL GEMM operands now): row m stores k-byte at
//   phys(m, k) = (k & ~63) | (((k>>3) + (m>>1)) & 7)*8 | (k & 7)
// -> LDS staging is a verbatim linear row copy; ds_read_b64 at slot (s + (row>>1))&7
//    puts a 16-lane quarter-group on all 32 banks exactly once (zero conflicts, r7-verified).
// Conv im2col reads rows shifted by tap: per-tap slot base hoisted OUTSIDE the inner
// K-loop (r7's in-loop recompute was the regression; r8's LDS-local rotation has a
// pigeonhole 2-way floor).
__device__ __forceinline__ int swz(int m, int k) {
    return (k & ~63) | (((((k >> 3) + (m >> 1)) & 7) << 3)) | (k & 7);
}

// async global->LDS, 16 B per lane; lds dest must be wave-uniform (HW adds lane*16)
__device__ __forceinline__ void gl_lds16(const u8* g, u8* l) {
    __builtin_amdgcn_global_load_lds(
        (const __attribute__((address_space(1))) void*)(const void*)g,
        (__attribute__((address_space(3))) void*)(void*)l,
        16, 0, 0);
}

// ---------------------------------------------------------------- merged prep: 4x cvt (f32->fp8,
// pre-swizzled), Sacc/nrm2 zero, 2x conv-weight reorder, zero page, H/W tail. One launch.
__device__ __forceinline__ void cvt4_body(const float* __restrict__ in, u8* __restrict__ out,
                                          int i, int Kp) {
    float4 f = ((const float4*)in)[i];
    uchar4 o; o.x = f2e4(f.x); o.y = f2e4(f.y); o.z = f2e4(f.z); o.w = f2e4(f.w);
    int e = i * 4;
    int n = e / Kp, k = e - n * Kp;              // 4 bytes stay inside one 8-B slot
    *(uchar4*)(out + (size_t)n * Kp + swz(n, k)) = o;
}
__device__ __forceinline__ void reord_body(const float* __restrict__ w, u8* __restrict__ wr,
                                           int i) {
    int o = i / 3456, rem = i - o * 3456;
    int j = rem / 384, c = rem - j * 384;
    wr[(size_t)o * 3456 + swz(o, rem)] = f2e4(w[(size_t)(o * 384 + c) * 9 + j]);
}

__global__ __launch_bounds__(256)
void prep_kernel(const float* __restrict__ w_qkv, u8* __restrict__ wqkvb,
                 const float* __restrict__ w_proj, u8* __restrict__ wprojb,
                 const float* __restrict__ mlp_w1, u8* __restrict__ w1b,
                 const float* __restrict__ mlp_w2, u8* __restrict__ w2b,
                 float* __restrict__ Sacc,                     // zero 307200 f32 (Sacc+nrm2)
                 const float* __restrict__ pconv1, u8* __restrict__ w1r,
                 const float* __restrict__ pconv2, u8* __restrict__ w2r,
                 unsigned int* __restrict__ zp,                // zero 1024 u32 (4 KB page)
                 const int* __restrict__ Hp, const int* __restrict__ Wp,
                 float* __restrict__ dout, size_t base, int n_extra) {
    int i = blockIdx.x * 256 + threadIdx.x;
    if (i < 110592)                   { cvt4_body(w_qkv, wqkvb, i, 384);  return; }
    if ((i -= 110592) < 36864)        { cvt4_body(w_proj, wprojb, i, 384); return; }
    if ((i -= 36864) < 73728)         { cvt4_body(mlp_w1, w1b, i, 384);   return; }
    if ((i -= 73728) < 73728)         { cvt4_body(mlp_w2, w2b, i, 768);   return; }
    if ((i -= 73728) < 307200)        { Sacc[i] = 0.f;                    return; }
    if ((i -= 307200) < 1327104)      { reord_body(pconv1, w1r, i);       return; }
    if ((i -= 1327104) < 1327104)     { reord_body(pconv2, w2r, i);       return; }
    if ((i -= 1327104) < 1024)        { zp[i] = 0u;                       return; }
    if ((i -= 1024) < 2) {
        if (i == 0 && n_extra >= 1) dout[base]     = (float)Hp[0];
        if (i == 1 && n_extra >= 2) dout[base + 1] = (float)Wp[0];
    }
}
#define PREP_TOTAL (110592 + 36864 + 73728 + 73728 + 307200 + 1327104 + 1327104 + 1024 + 2)

// ---------------------------------------------------------------- LayerNorm over C=384 -> fp8
// 256-thr blocks, 4 waves, one row per wave. Always pre-swizzled output (all consumers
// now read the 8-slot layout, including the im2col convs).
__global__ __launch_bounds__(256)
void ln_kernel(const float* __restrict__ xf, const float* __restrict__ g,
               const float* __restrict__ b, u8* __restrict__ out) {
    const int row = blockIdx.x * 4 + (threadIdx.x >> 6);
    const int lane = threadIdx.x & 63;
    const float* xr = xf + (size_t)row * 384;
    float v[6], s = 0.f, s2 = 0.f;
#pragma unroll
    for (int i = 0; i < 6; ++i) { v[i] = xr[lane + i * 64]; s += v[i]; s2 += v[i] * v[i]; }
#pragma unroll
    for (int off = 32; off; off >>= 1) { s += __shfl_xor(s, off); s2 += __shfl_xor(s2, off); }
    float mean = s * (1.0f / 384.0f);
    float var  = s2 * (1.0f / 384.0f) - mean * mean;
    float rstd = rsqrtf(var + LN_EPS);
    u8* orow = out + (size_t)row * 384;
    const int gperm = (row >> 1) & 7;
    const int pofs = ((((lane >> 3) + gperm) & 7) << 3) | (lane & 7);
#pragma unroll
    for (int i = 0; i < 6; ++i) {
        int c = lane + i * 64;
        orow[i * 64 + pofs] = f2e4((v[i] - mean) * rstd * g[c] + b[c]);
    }
}

// ---------------------------------------------------------------- MFMA NT GEMM (fp8 e4m3 A,B): C = A[M,K] * B[N,K]^T
// 128x128 tile, BK=64, 256 thr / 4 waves (64x64/wave), dbuf LDS 32 KB -> 4 blk/CU.
// ALL operands globally pre-swizzled (swz) -> linear staging + 8-slot read = ZERO bank
// conflicts. Conv im2col: tap(9) x tile(6) NESTED loops; per-tap A-slot offsets (ca0/ca1)
// computed once per tap OUTSIDE the inner loop (r7 formula, hoisted).
// Sync = r2's proven minimal loop: {mfma; lgkm0; bar; STAGE(t+2); counted vmcnt(4); bar}.
// No setprio (r9 A/B: -3.5% on GEMM, consistent with m190).
// ACONV: 0 plain A[M,K]; 1 implicit im2col (H=W=48, K=3456), source pre-swizzled.
// EPI: 0 bf16 store; 1 BN+GELU->fp8 pre-swizzled; 2 BN -> xf += gamma*v; 3 xf += gamma*v;
//      4 ofb = xf + gamma*v; 5 xf = xin + gamma*v
template<int ACONV, int EPI>
__global__ __launch_bounds__(256, 4)
void gemm_nt(const u8* __restrict__ A, const u8* __restrict__ Bm,
             int M, int N, int K,
             u16* __restrict__ Obf, int ldo,
             float* __restrict__ xf, float* __restrict__ ofb, const float* __restrict__ xin,
             const float* __restrict__ bn_g, const float* __restrict__ bn_b,
             const float* __restrict__ bn_m, const float* __restrict__ bn_v,
             const float* __restrict__ gamma, const u8* __restrict__ zp) {
    __shared__ u8 As[2][128 * 64];
    __shared__ u8 Bs[2][128 * 64];

    const int tid = threadIdx.x;
    // XCD swizzle: L = (g%8)*(G/8) + g/8 ; n_tile = L % gx (fast), m_tile = L / gx
    const int gx = gridDim.x;
    const int g  = blockIdx.y * gx + blockIdx.x;
    const int G  = gx * gridDim.y;
    int L = g;
    if ((G & 7) == 0) L = (g & 7) * (G >> 3) + (g >> 3);
    const int n0 = (L % gx) * 128;
    const int m0 = (L / gx) * 128;

    const int lane  = tid & 63;
    const int wave  = tid >> 6;
    const int wm    = (wave >> 1) * 64;
    const int wn    = (wave & 1) * 64;
    const int fr    = lane & 15;
    const int klane = lane >> 4;

    const int hE = fr >> 1;                  // per-lane slot term, even tap-shift
    const int hO = ((fr + 1) >> 1) & 7;      // per-lane slot term, odd tap-shift

    int arow[4], brow[4];
#pragma unroll
    for (int i = 0; i < 4; ++i) {
        arow[i] = (wm + i * 16 + fr) * 64;
        brow[i] = (wn + i * 16 + fr) * 64;
    }
    // 8-slot pre-swizzle read (B always; A when ACONV=0): slot = (kh*4 + klane + fr>>1) & 7
    int csw8[2];
#pragma unroll
    for (int kh = 0; kh < 2; ++kh)
        csw8[kh] = ((((kh << 2) + klane) + hE) & 7) << 3;

    // staging: verbatim linear copy (all sources pre-swizzled)
    const int srow = tid >> 2;
    const int scol = (tid & 3) << 4;
    const u8 *sa[2], *sb[2];
    const u8* imgq[2];
    int ay[2], ax[2];
#pragma unroll
    for (int q = 0; q < 2; ++q) {
        int r = q * 64 + srow;
        if (ACONV == 0) {
            sa[q] = A + (size_t)(m0 + r) * K + scol;
        } else {
            int nA = m0 + r;
            int bi = nA / 2304;                  // 128-tile never crosses image (128 | 2304)
            int nl = nA - bi * 2304;
            ay[q] = nl / 48;
            ax[q] = nl - ay[q] * 48;
            imgq[q] = A + (size_t)bi * 2304 * 384;
        }
        sb[q] = Bm + (size_t)(n0 + q * 64 + srow) * K + scol;
    }

    int scnt = 0, sjj = 0;
    const int NT = K / 64;

    auto STAGE = [&](int d) {
        if (ACONV == 1) {
            if (scnt == 0) {                     // new 3x3 tap: recompute A pointers
                int t3 = sjj / 3;
                int dy = t3 - 1, dx = sjj - t3 * 3 - 1;
                ++sjj;
#pragma unroll
                for (int q = 0; q < 2; ++q) {
                    int yy = ay[q] + dy, xx = ax[q] + dx;
                    bool v = ((unsigned)yy < 48u) & ((unsigned)xx < 48u);
                    sa[q] = (v ? imgq[q] + (size_t)(yy * 48 + xx) * 384 : zp) + scol;
                }
            }
            scnt = (scnt == 5) ? 0 : scnt + 1;
        }
        u8* la = &As[d][0];
        u8* lb = &Bs[d][0];
        gl_lds16(sa[0], la + ((wave * 64) << 4));        sa[0] += 64;
        gl_lds16(sa[1], la + ((256 + wave * 64) << 4));  sa[1] += 64;
        gl_lds16(sb[0], lb + ((wave * 64) << 4));        sb[0] += 64;
        gl_lds16(sb[1], lb + ((256 + wave * 64) << 4));  sb[1] += 64;
    };

    floatx4 acc[4][4];
#pragma unroll
    for (int i = 0; i < 4; ++i)
#pragma unroll
        for (int j = 0; j < 4; ++j) acc[i][j] = (floatx4){0.f, 0.f, 0.f, 0.f};

    // prologue: tiles 0,1 in flight (4 loads each per thread); counted wait on tile 0 only
    STAGE(0);
    STAGE(1);
    asm volatile("s_waitcnt vmcnt(4)" ::: "memory");
    __builtin_amdgcn_s_barrier();
    asm volatile("" ::: "memory");

    int cur = 0;
    auto KSTEP = [&](int a0, int a1, int t) {
        const u8* Ab = &As[cur][0];
        const u8* Bb = &Bs[cur][0];
        {
            long af[4], bfr[4];
#pragma unroll
            for (int i = 0; i < 4; ++i) af[i]  = *(const long*)(Ab + arow[i] + a0);
#pragma unroll
            for (int j = 0; j < 4; ++j)  bfr[j] = *(const long*)(Bb + brow[j] + csw8[0]);
#pragma unroll
            for (int i = 0; i < 4; ++i)
#pragma unroll
                for (int j = 0; j < 4; ++j)
                    acc[i][j] = __builtin_amdgcn_mfma_f32_16x16x32_fp8_fp8(af[i], bfr[j], acc[i][j], 0, 0, 0);
        }
        {
            long af[4], bfr[4];
#pragma unroll
            for (int i = 0; i < 4; ++i) af[i]  = *(const long*)(Ab + arow[i] + a1);
#pragma unroll
            for (int j = 0; j < 4; ++j)  bfr[j] = *(const long*)(Bb + brow[j] + csw8[1]);
#pragma unroll
            for (int i = 0; i < 4; ++i)
#pragma unroll
                for (int j = 0; j < 4; ++j)
                    acc[i][j] = __builtin_amdgcn_mfma_f32_16x16x32_fp8_fp8(af[i], bfr[j], acc[i][j], 0, 0, 0);
        }
        asm volatile("s_waitcnt lgkmcnt(0)" ::: "memory");   // this wave's reads of buf[cur] done
        __builtin_amdgcn_s_barrier();                        // all waves done -> buf[cur] free
        asm volatile("" ::: "memory");
        if (t + 2 < NT) {
            STAGE(cur);                                      // issue tile t+2 into freed buffer
            asm volatile("s_waitcnt vmcnt(4)" ::: "memory"); // drain tile t+1 (issued 1 tile ago)
        } else {
            asm volatile("s_waitcnt vmcnt(0)" ::: "memory"); // tail: nothing new issued
        }
        __builtin_amdgcn_sched_barrier(0);
        __builtin_amdgcn_s_barrier();                        // tile t+1 resident for all waves
        asm volatile("" ::: "memory");
        cur ^= 1;
    };

    if (ACONV == 0) {
        for (int t = 0; t < NT; ++t) KSTEP(csw8[0], csw8[1], t);
    } else {
        // tap-hoisted: per-tap A slot base computed OUTSIDE the 6-tile inner loop.
        // A source row g = (mult of 16) + fr + shift -> slot base = ((fr+shift)>>1) mod 8
        //  = (shift even ? hE : hO) + (shift>>1), all mod 8.  (+4608 keeps shift positive)
        int t = 0;
        for (int tap = 0; tap < 9; ++tap) {
            int t3 = tap / 3;
            int shift = (t3 - 1) * 48 + (tap - t3 * 3 - 1) + 4608;
            int cc = (shift >> 1) & 7;
            int h  = (shift & 1) ? hO : hE;
            int ca0 = ((klane + h + cc) & 7) << 3;
            int ca1 = ((4 + klane + h + cc) & 7) << 3;
            for (int tt = 0; tt < 6; ++tt, ++t) KSTEP(ca0, ca1, t);
        }
    }

    // Epilogue. C/D layout: col = lane&15, row = (lane>>4)*4 + reg  [dtype-independent, m121-128]
    const int quad4 = (lane >> 4) * 4;
#pragma unroll
    for (int j = 0; j < 4; ++j) {
        int col = n0 + wn + j * 16 + fr;
        float bscale = 0.f, bshift = 0.f, gam = 0.f;
        if (EPI == 1 || EPI == 2) {
            bscale = bn_g[col] * rsqrtf(bn_v[col] + LN_EPS);
            bshift = bn_b[col] - bn_m[col] * bscale;
        }
        if (EPI >= 2) gam = gamma[col];
#pragma unroll
        for (int i = 0; i < 4; ++i) {
#pragma unroll
            for (int r = 0; r < 4; ++r) {
                int row = m0 + wm + i * 16 + quad4 + r;
                float v = acc[i][j][r];
                if (EPI == 0) {
                    Obf[(size_t)row * ldo + col] = f2bf(v);
                } else if (EPI == 1) {
                    float t = v * bscale + bshift;
                    t = 0.5f * t * (1.0f + erff(t * 0.70710678118654752f));
                    ((u8*)Obf)[(size_t)row * ldo + swz(row, col)] = f2e4(t);  // feeds GEMM-A
                } else if (EPI == 2) {
                    float t = v * bscale + bshift;
                    xf[(size_t)row * N + col] += gam * t;
                } else if (EPI == 3) {
                    xf[(size_t)row * N + col] += gam * v;
                } else if (EPI == 4) {
                    ofb[(size_t)row * N + col] = xf[(size_t)row * N + col] + gam * v;
                } else {
                    xf[(size_t)row * N + col] = xin[(size_t)row * N + col] + gam * v;
                }
            }
        }
    }
}

// ---------------------------------------------------------------- channel attention, stage 1:
// partial Gram + partial norms over a 128-row N-slice; atomicAdd into f32 accumulators.
// grid (18 slices, 128 bh). qkv stays bf16 (EPI=0 output, NOT swizzled).
__global__ __launch_bounds__(256)
void gram_kernel(const u16* __restrict__ qkv, float* __restrict__ Sacc,
                 float* __restrict__ nrm2) {
    const int bh = blockIdx.y;
    const int b = bh >> 3, h = bh & 7;
    const int tid = threadIdx.x;
    __shared__ float qsf[64][48];
    __shared__ float ksf[64][48];

    float acc9[3][3];
#pragma unroll
    for (int i = 0; i < 3; ++i)
#pragma unroll
        for (int j = 0; j < 3; ++j) acc9[i][j] = 0.f;
    float qn2 = 0.f, kn2 = 0.f;

    const int qoff = h * 48;
    const int koff = 384 + h * 48;
    const int d0 = (tid >> 4) * 3;
    const int e0 = (tid & 15) * 3;
    const int nbase = blockIdx.x * 128;

    for (int c = 0; c < 2; ++c) {
        const int n0 = nbase + c * 64;
#pragma unroll
        for (int it = 0; it < 6; ++it) {
            int chunk = tid + it * 256;          // 0..1535: [q 768 | k 768] chunks of 4 bf16
            int mat = chunk >= 768 ? 1 : 0;
            int rem = chunk - mat * 768;
            int nn = rem / 12, u = rem - nn * 12;
            ushort4 raw = *(const ushort4*)(qkv + (size_t)(b * 2304 + n0 + nn) * 1152 +
                                            (mat ? koff : qoff) + u * 4);
            float4 f = make_float4(bf2f(raw.x), bf2f(raw.y), bf2f(raw.z), bf2f(raw.w));
            if (mat) *(float4*)&ksf[nn][u * 4] = f;
            else     *(float4*)&qsf[nn][u * 4] = f;
        }
        __syncthreads();
#pragma unroll 4
        for (int nn = 0; nn < 64; ++nn) {
            float q0 = qsf[nn][d0], q1 = qsf[nn][d0 + 1], q2 = qsf[nn][d0 + 2];
            float k0v = ksf[nn][e0], k1v = ksf[nn][e0 + 1], k2v = ksf[nn][e0 + 2];
            acc9[0][0] += q0 * k0v; acc9[0][1] += q0 * k1v; acc9[0][2] += q0 * k2v;
            acc9[1][0] += q1 * k0v; acc9[1][1] += q1 * k1v; acc9[1][2] += q1 * k2v;
            acc9[2][0] += q2 * k0v; acc9[2][1] += q2 * k1v; acc9[2][2] += q2 * k2v;
        }
        if (tid < 48) {
            for (int nn = 0; nn < 64; ++nn) { float q = qsf[nn][tid]; qn2 += q * q; }
        } else if (tid >= 128 && tid < 176) {
            int e = tid - 128;
            for (int nn = 0; nn < 64; ++nn) { float k = ksf[nn][e]; kn2 += k * k; }
        }
        __syncthreads();
    }

    float* Sb = Sacc + (size_t)bh * 2304;
#pragma unroll
    for (int i = 0; i < 3; ++i)
#pragma unroll
        for (int j = 0; j < 3; ++j)
            atomicAdd(&Sb[(d0 + i) * 48 + e0 + j], acc9[i][j]);
    if (tid < 48) atomicAdd(&nrm2[bh * 96 + tid], qn2);
    else if (tid >= 128 && tid < 176) atomicAdd(&nrm2[bh * 96 + 48 + (tid - 128)], kn2);
}

// ---------------------------------------------------------------- fused attention finalize + PV:
// per block: softmax(48x48) from Sacc/nrm2 (36x redundant per bh, L2-served), then
// out[b,n,h*48+d] = sum_e attn[d][e] * v[b,n,h*48+e]; z written fp8 PRE-SWIZZLED.
__global__ __launch_bounds__(256)
void attnout_kernel(const u16* __restrict__ qkv, const float* __restrict__ Sacc,
                    const float* __restrict__ nrm2, const float* __restrict__ temp,
                    u8* __restrict__ z) {
    const int r0 = blockIdx.x * 64;
    const int h  = blockIdx.y;
    const int b  = r0 / 2304;
    const int bh = b * 8 + h;
    const int tid = threadIdx.x;
    __shared__ float A[48][49];
    __shared__ float vsf[64][48];
    __shared__ float qns[48], kns[48];

    const float* Sb = Sacc + (size_t)bh * 2304;
    for (int i = tid; i < 2304; i += 256) {
        int d = i / 48, e = i - d * 48;
        A[d][e] = Sb[i];
    }
    if (tid < 48)      qns[tid]      = fmaxf(sqrtf(nrm2[bh * 96 + tid]), 1e-12f);
    else if (tid < 96) kns[tid - 48] = fmaxf(sqrtf(nrm2[bh * 96 + tid]), 1e-12f);
    const int voff = 768 + h * 48;
    for (int i = tid; i < 768; i += 256) {
        int nn = i / 12, u = i - nn * 12;
        ushort4 raw = *(const ushort4*)(qkv + (size_t)(r0 + nn) * 1152 + voff + u * 4);
        float4 f = make_float4(bf2f(raw.x), bf2f(raw.y), bf2f(raw.z), bf2f(raw.w));
        *(float4*)&vsf[nn][u * 4] = f;
    }
    __syncthreads();

    if (tid < 48) {                              // row softmax in LDS, in place
        float tf = temp[h] / qns[tid];
        float mx = -1e30f;
        for (int e = 0; e < 48; ++e) {
            float t = A[tid][e] * tf / kns[e];
            A[tid][e] = t;
            mx = fmaxf(mx, t);
        }
        float sum = 0.f;
        for (int e = 0; e < 48; ++e) { float t = __expf(A[tid][e] - mx); A[tid][e] = t; sum += t; }
        float inv = 1.0f / sum;
        for (int e = 0; e < 48; ++e) A[tid][e] *= inv;
    }
    __syncthreads();

    const int rr0 = (tid >> 4) * 4;
    const int d0  = (tid & 15) * 3;
    float acc[4][3];
#pragma unroll
    for (int r = 0; r < 4; ++r)
#pragma unroll
        for (int j = 0; j < 3; ++j) acc[r][j] = 0.f;

#pragma unroll 4
    for (int e = 0; e < 48; ++e) {
        float a0 = A[d0][e], a1 = A[d0 + 1][e], a2 = A[d0 + 2][e];
#pragma unroll
        for (int r = 0; r < 4; ++r) {
            float vv = vsf[rr0 + r][e];
            acc[r][0] += a0 * vv; acc[r][1] += a1 * vv; acc[r][2] += a2 * vv;
        }
    }
#pragma unroll
    for (int r = 0; r < 4; ++r)
#pragma unroll
        for (int j = 0; j < 3; ++j) {
            int row = r0 + rr0 + r;
            int col = h * 48 + d0 + j;
            z[(size_t)row * 384 + swz(row, col)] = f2e4(acc[r][j]);
        }
}

extern "C" void kernel_launch(void* const* d_in, const int* in_sizes, int n_in,
                              void* d_out, int out_size, void* d_ws, size_t ws_size,
                              hipStream_t stream) {
    const float* x      = (const float*)d_in[0];
    const float* ln1_g  = (const float*)d_in[1];
    const float* ln1_b  = (const float*)d_in[2];
    const float* w_qkv  = (const float*)d_in[3];
    const float* temp   = (const float*)d_in[4];
    const float* w_proj = (const float*)d_in[5];
    const float* gamma1 = (const float*)d_in[6];
    const float* ln2_g  = (const float*)d_in[7];
    const float* ln2_b  = (const float*)d_in[8];
    const float* mlp_w1 = (const float*)d_in[9];
    const float* bn1_g  = (const float*)d_in[10];
    const float* bn1_b  = (const float*)d_in[11];
    const float* bn1_m  = (const float*)d_in[12];
    const float* bn1_v  = (const float*)d_in[13];
    const float* mlp_w2 = (const float*)d_in[14];
    const float* bn2_g  = (const float*)d_in[15];
    const float* bn2_b  = (const float*)d_in[16];
    const float* bn2_m  = (const float*)d_in[17];
    const float* bn2_v  = (const float*)d_in[18];
    const float* gamma2 = (const float*)d_in[19];
    const float* ln3_g  = (const float*)d_in[20];
    const float* ln3_b  = (const float*)d_in[21];
    const float* pconv1 = (const float*)d_in[22];
    const float* pbn_g  = (const float*)d_in[23];
    const float* pbn_b  = (const float*)d_in[24];
    const float* pbn_m  = (const float*)d_in[25];
    const float* pbn_v  = (const float*)d_in[26];
    const float* pconv2 = (const float*)d_in[27];
    const float* gamma3 = (const float*)d_in[28];
    const int* Hp = (const int*)d_in[29];
    const int* Wp = (const int*)d_in[30];

    const int M = 36864, C = 384, C2 = 768, NQKV = 1152, KC = 3456;
    const size_t NBNC = (size_t)M * C;                 // 14,155,776

    const size_t SZ_XF  = NBNC * 4;                    //  f32 residual stream
    const size_t SZ_LN  = NBNC * 2;                    //  fp8 LN out / z (half used)
    const size_t SZ_BIG = (size_t)M * NQKV * 2;        //  bf16 qkv / fp8 mlp hidden
    const size_t SZ_P3  = SZ_LN;                       //  weights + Gram accum, later conv1 out
    const size_t SZ_W   = (size_t)C * KC * 2;
    if (ws_size < SZ_XF + SZ_LN + SZ_BIG + SZ_P3 + 2 * SZ_W + 4096) return;

    char* ws = (char*)d_ws;
    float* xf     = (float*)ws;
    u8*    lnbuf  = (u8*)(ws + SZ_XF);
    u16*   big    = (u16*)(ws + SZ_XF + SZ_LN);
    char*  p3     = ws + SZ_XF + SZ_LN + SZ_BIG;
    u8*    wqkvb  = (u8*)(p3 + 1179648);
    u8*    wprojb = (u8*)(p3 + 1179648 + 884736);
    u8*    w1b    = (u8*)(p3 + 1179648 + 884736 + 294912);
    u8*    w2b    = (u8*)(p3 + 1179648 + 884736 + 294912 + 589824);
    float* Sacc   = (float*)(p3 + 3538944);                          // 128*2304 f32
    float* nrm2   = (float*)(p3 + 3538944 + 1179648);                // 128*96 f32 (contiguous)
    u8*    convbf = (u8*)p3;                                         // conv1 output (fp8, M*C), block 3 only
    u8*    w1r    = (u8*)(p3 + SZ_P3);
    u8*    w2r    = (u8*)(p3 + SZ_P3 + SZ_W);
    u8*    zpg    = (u8*)(p3 + SZ_P3 + 2 * SZ_W);                    // dedicated 4 KB zero page

    const int n_extra = out_size - (int)NBNC;

    // merged prep: all weight cvt/reorder + accumulator zero + zero page + H/W tail (1 launch)
    prep_kernel<<<(PREP_TOTAL + 255) / 256, 256, 0, stream>>>(
        w_qkv, wqkvb, w_proj, wprojb, mlp_w1, w1b, mlp_w2, w2b,
        Sacc, pconv1, w1r, pconv2, w2r, (unsigned int*)zpg,
        Hp, Wp, (float*)d_out, NBNC, n_extra);

    // --- attention block ---  (ln1 reads input x directly)
    ln_kernel<<<M / 4, 256, 0, stream>>>(x, ln1_g, ln1_b, lnbuf);
    gemm_nt<0, 0><<<dim3(NQKV / 128, M / 128), 256, 0, stream>>>(
        lnbuf, wqkvb, M, NQKV, C, big, NQKV, nullptr, nullptr, nullptr,
        nullptr, nullptr, nullptr, nullptr, nullptr, nullptr);
    gram_kernel<<<dim3(18, 128), 256, 0, stream>>>(big, Sacc, nrm2);
    attnout_kernel<<<dim3(M / 64, 8), 256, 0, stream>>>(big, Sacc, nrm2, temp, lnbuf);
    gemm_nt<0, 5><<<dim3(C / 128, M / 128), 256, 0, stream>>>(        // xf = x + gamma1 * proj
        lnbuf, wprojb, M, C, C, nullptr, 0, xf, nullptr, x,
        nullptr, nullptr, nullptr, nullptr, gamma1, nullptr);

    // --- ConvMlp block (1x1 convs + eval BN) ---
    ln_kernel<<<M / 4, 256, 0, stream>>>(xf, ln2_g, ln2_b, lnbuf);
    gemm_nt<0, 1><<<dim3(C2 / 128, M / 128), 256, 0, stream>>>(
        lnbuf, w1b, M, C2, C, (u16*)big, C2, nullptr, nullptr, nullptr,
        bn1_g, bn1_b, bn1_m, bn1_v, nullptr, nullptr);
    gemm_nt<0, 2><<<dim3(C / 128, M / 128), 256, 0, stream>>>(
        (u8*)big, w2b, M, C, C2, nullptr, 0, xf, nullptr, nullptr,
        bn2_g, bn2_b, bn2_m, bn2_v, gamma2, nullptr);

    // --- projection block (3x3 conv -> BN -> GELU -> 3x3 conv), implicit im2col GEMMs ---
    ln_kernel<<<M / 4, 256, 0, stream>>>(xf, ln3_g, ln3_b, lnbuf);     // swizzled (conv1 A source)
    gemm_nt<1, 1><<<dim3(C / 128, M / 128), 256, 0, stream>>>(         // convbf swizzled (conv2 A source)
        lnbuf, w1r, M, C, KC, (u16*)convbf, C, nullptr, nullptr, nullptr,
        pbn_g, pbn_b, pbn_m, pbn_v, nullptr, zpg);
    gemm_nt<1, 4><<<dim3(C / 128, M / 128), 256, 0, stream>>>(
        convbf, w2r, M, C, KC, nullptr, 0, xf, (float*)d_out, nullptr,
        nullptr, nullptr, nullptr, nullptr, gamma3, zpg);
}